// Round 13
// baseline (484.229 us; speedup 1.0000x reference)
//
#include <hip/hip_runtime.h>

#define NNODES 100000
#define NEDGES 1600000
#define DDIM   128
#define NBUK ((NNODES + 127) / 128)        // 782 buckets of 128 nodes
#define EB   8192                          // edges per sort block
#define NBLK_E ((NEDGES + EB - 1) / EB)    // 196

typedef __attribute__((ext_vector_type(8))) short short8;
typedef __attribute__((ext_vector_type(4))) float f32x4;
typedef __attribute__((ext_vector_type(2))) float f32x2;

// f32 -> bf16 round-to-nearest-even (bit trick; NaN irrelevant here)
__device__ __forceinline__ unsigned short f2bf(float f) {
    unsigned u = __float_as_uint(f);
    u += 0x7FFFu + ((u >> 16) & 1u);
    return (unsigned short)(u >> 16);
}

// ---------------- CSR build: deterministic bucketed counting sort ----------------
// No per-edge GLOBAL atomics anywhere (round-5 lesson: 1.6M atomics / 782 addrs
// serialize at ~210ns per same-line RMW = 431us). All per-edge atomics are LDS.

__global__ void __launch_bounds__(256) p1_hist(const int* __restrict__ dst,
                                               int* __restrict__ histmat) {
    __shared__ int h[NBUK];
    for (int i = threadIdx.x; i < NBUK; i += 256) h[i] = 0;
    __syncthreads();
    int base = blockIdx.x * EB;
    int end = base + EB; if (end > NEDGES) end = NEDGES;
    for (int i = base + threadIdx.x; i < end; i += 256)
        atomicAdd(&h[dst[i] >> 7], 1);
    __syncthreads();
    for (int i = threadIdx.x; i < NBUK; i += 256)
        histmat[blockIdx.x * NBUK + i] = h[i];
}

__global__ void __launch_bounds__(256) p2_colscan(const int* __restrict__ histmat,
                                                  int* __restrict__ colofs,
                                                  int* __restrict__ totals) {
    int b = blockIdx.x * 4 + (threadIdx.x >> 6);
    if (b >= NBUK) return;
    int lane = threadIdx.x & 63;
    int running = 0;
    #pragma unroll
    for (int r = 0; r < (NBLK_E + 63) / 64; ++r) {
        int blk = r * 64 + lane;
        int v = (blk < NBLK_E) ? histmat[blk * NBUK + b] : 0;
        int sc = v;
        for (int o = 1; o < 64; o <<= 1) {
            int u = __shfl_up(sc, o);
            if (lane >= o) sc += u;
        }
        if (blk < NBLK_E) colofs[blk * NBUK + b] = running + sc - v;
        running += __shfl(sc, 63);
    }
    if (lane == 0) totals[b] = running;
}

__global__ void __launch_bounds__(1024) p2b_bscan(const int* __restrict__ totals,
                                                  int* __restrict__ bbase,
                                                  int* __restrict__ rowptr) {
    __shared__ int sm[1024];
    int t = threadIdx.x;
    int v = (t < NBUK) ? totals[t] : 0;
    sm[t] = v;
    __syncthreads();
    for (int o = 1; o < 1024; o <<= 1) {
        int u = (t >= o) ? sm[t - o] : 0;
        __syncthreads();
        sm[t] += u;
        __syncthreads();
    }
    if (t < NBUK) bbase[t] = sm[t] - v;
    if (t == 0) { bbase[NBUK] = NEDGES; rowptr[NNODES] = NEDGES; }
}

__global__ void __launch_bounds__(256) p3_bucket(const int* __restrict__ src,
                                                 const int* __restrict__ dst,
                                                 const int* __restrict__ colofs,
                                                 const int* __restrict__ bbase,
                                                 unsigned* __restrict__ ebuf) {
    __shared__ int cur[NBUK];
    for (int i = threadIdx.x; i < NBUK; i += 256)
        cur[i] = bbase[i] + colofs[blockIdx.x * NBUK + i];
    __syncthreads();
    int base = blockIdx.x * EB;
    int end = base + EB; if (end > NEDGES) end = NEDGES;
    for (int i = base + threadIdx.x; i < end; i += 256) {
        int d = dst[i];
        int pos = atomicAdd(&cur[d >> 7], 1);
        ebuf[pos] = ((unsigned)(d & 127) << 17) | (unsigned)src[i];
    }
}

__global__ void __launch_bounds__(256) p4_final(const unsigned* __restrict__ ebuf,
                                                const int* __restrict__ bbase,
                                                int* __restrict__ rowptr,
                                                int* __restrict__ sorted) {
    __shared__ int cnt[128];
    __shared__ int ofs[128];
    int b = blockIdx.x;
    int s = bbase[b], e = bbase[b + 1];
    int t = threadIdx.x;
    if (t < 128) cnt[t] = 0;
    __syncthreads();
    for (int i = s + t; i < e; i += 256)
        atomicAdd(&cnt[ebuf[i] >> 17], 1);
    __syncthreads();
    if (t < 128) ofs[t] = cnt[t];
    __syncthreads();
    for (int o = 1; o < 128; o <<= 1) {
        int u = (t >= o && t < 128) ? ofs[t - o] : 0;
        __syncthreads();
        if (t < 128) ofs[t] += u;
        __syncthreads();
    }
    int nodebase = b << 7;
    if (t < 128) {
        int excl = ofs[t] - cnt[t];
        if (nodebase + t < NNODES) rowptr[nodebase + t] = s + excl;
        cnt[t] = excl;  // reuse as cursor
    }
    __syncthreads();
    for (int i = s + t; i < e; i += 256) {
        unsigned v = ebuf[i];
        int r = atomicAdd(&cnt[v >> 17], 1);
        sorted[s + r] = (int)(v & 0x1FFFFu);
    }
}

// ---------------- dtype prep ----------------

__global__ void sage_cvt(const float* __restrict__ in, unsigned short* __restrict__ out, int n) {
    int i = (blockIdx.x * blockDim.x + threadIdx.x) * 4;
    if (i < n) {
        float4 v = *(const float4*)&in[i];
        uint2 o;
        o.x = (unsigned)f2bf(v.x) | ((unsigned)f2bf(v.y) << 16);
        o.y = (unsigned)f2bf(v.z) | ((unsigned)f2bf(v.w) << 16);
        *(uint2*)&out[i] = o;
    }
}

__global__ void sage_wprep2(const float* __restrict__ W1l, const float* __restrict__ W1r,
                            const float* __restrict__ W2l, const float* __restrict__ W2r,
                            unsigned short* __restrict__ wc1, unsigned short* __restrict__ wc2) {
    int idx = blockIdx.x * blockDim.x + threadIdx.x;  // 0..65535
    int which = idx >> 15;
    int id = idx & 32767;
    int j = id >> 8, k = id & 255;
    const float* Wl = which ? W2l : W1l;
    const float* Wr = which ? W2r : W1r;
    unsigned short* o = which ? wc2 : wc1;
    float v = (k < 128) ? Wl[j * 128 + k] : Wr[j * 128 + (k - 128)];
    o[id] = f2bf(v);
}

// ---------------- aggregation (one wave per node, dwordx4 gather) ----------------

__global__ void __launch_bounds__(256) sage_aggr(const unsigned short* __restrict__ in,
                                                 const int* __restrict__ rowptr,
                                                 const int* __restrict__ srcs,
                                                 unsigned short* __restrict__ ag) {
    int node = blockIdx.x * 4 + (threadIdx.x >> 6);
    if (node >= NNODES) return;
    int lane = threadIdx.x & 63;
    int g = lane >> 4, s = lane & 15;
    int beg = rowptr[node], end = rowptr[node + 1];
    const uint4* inq = (const uint4*)in;   // 16 uint4 per row
    f32x2 f0 = {0.f, 0.f}, f1 = {0.f, 0.f}, f2 = {0.f, 0.f}, f3 = {0.f, 0.f};

    auto accum = [&](uint4 v) {
        f0 += (f32x2){__uint_as_float(v.x << 16), __uint_as_float(v.x & 0xFFFF0000u)};
        f1 += (f32x2){__uint_as_float(v.y << 16), __uint_as_float(v.y & 0xFFFF0000u)};
        f2 += (f32x2){__uint_as_float(v.z << 16), __uint_as_float(v.z & 0xFFFF0000u)};
        f3 += (f32x2){__uint_as_float(v.w << 16), __uint_as_float(v.w & 0xFFFF0000u)};
    };

    int i = beg;
    for (; i + 16 <= end; i += 16) {
        uint4 va = inq[srcs[i + g] * 16 + s];
        uint4 vb = inq[srcs[i + 4 + g] * 16 + s];
        uint4 vc = inq[srcs[i + 8 + g] * 16 + s];
        uint4 vd = inq[srcs[i + 12 + g] * 16 + s];
        accum(va); accum(vb); accum(vc); accum(vd);
    }
    for (; i + 4 <= end; i += 4)
        accum(inq[srcs[i + g] * 16 + s]);
    if (i + g < end)
        accum(inq[srcs[i + g] * 16 + s]);

    f0.x += __shfl_xor(f0.x, 16); f0.y += __shfl_xor(f0.y, 16);
    f1.x += __shfl_xor(f1.x, 16); f1.y += __shfl_xor(f1.y, 16);
    f2.x += __shfl_xor(f2.x, 16); f2.y += __shfl_xor(f2.y, 16);
    f3.x += __shfl_xor(f3.x, 16); f3.y += __shfl_xor(f3.y, 16);
    f0.x += __shfl_xor(f0.x, 32); f0.y += __shfl_xor(f0.y, 32);
    f1.x += __shfl_xor(f1.x, 32); f1.y += __shfl_xor(f1.y, 32);
    f2.x += __shfl_xor(f2.x, 32); f2.y += __shfl_xor(f2.y, 32);
    f3.x += __shfl_xor(f3.x, 32); f3.y += __shfl_xor(f3.y, 32);

    int cnt = end - beg;
    float inv = (cnt > 0) ? 1.0f / (float)cnt : 0.0f;
    if (g == 0) {
        uint4 o;
        o.x = (unsigned)f2bf(f0.x * inv) | ((unsigned)f2bf(f0.y * inv) << 16);
        o.y = (unsigned)f2bf(f1.x * inv) | ((unsigned)f2bf(f1.y * inv) << 16);
        o.z = (unsigned)f2bf(f2.x * inv) | ((unsigned)f2bf(f2.y * inv) << 16);
        o.w = (unsigned)f2bf(f3.x * inv) | ((unsigned)f2bf(f3.y * inv) << 16);
        ((uint4*)ag)[node * 16 + s] = o;
    }
}

// ---------------- GEMM: out[i][j] = sum_k Acat[i][k]*W[j][k] + bias[j] ----------------
// (1) XOR-swizzle LDS (col ^= (row&7)<<4): kills the 16-way bank conflict from
//     the 128B row stride (residual 2-way is free, m136).
// (2) Double-buffered REGISTER staging: load_tile(kt+1) issues its 8 dwordx4
//     loads before kt's barrier+MFMA phase -> latency hides under compute.
//     Staging coverage check: 256 thr x 4 chunks x 16B = 16KB = full tile.
// EPI 0: relu + bf16 store.  EPI 1: f32 store with fused row L2-normalize.

__device__ __forceinline__ int swz(int byteoff) {
    return byteoff ^ ((byteoff >> 3) & 0x70);   // col2 ^= (row&7)<<4
}

template <int EPI>
__global__ void __launch_bounds__(256) sage_gemm(const unsigned short* __restrict__ A0,
                                                 const unsigned short* __restrict__ A1,
                                                 const unsigned short* __restrict__ W,
                                                 const float* __restrict__ bias,
                                                 void* __restrict__ outp) {
    __shared__ unsigned short As[128 * 64];
    __shared__ unsigned short Bs[128 * 64];
    __shared__ float rss[128][2];
    const int tid = threadIdx.x;
    const int bm = blockIdx.x * 128;

    char* AsB = (char*)As;
    char* BsB = (char*)Bs;

    auto load_tile = [&](int kt, uint4* aR, uint4* bR) {
        const unsigned short* Asrc = (kt < 2) ? A0 : A1;
        int kofs = (kt & 1) * 64;
        #pragma unroll
        for (int it = 0; it < 4; ++it) {
            int idx = it * 2048 + tid * 8;        // short index in [0,8192)
            int r = idx >> 6, k = idx & 63;       // full 128 rows covered
            int row = bm + r; if (row >= NNODES) row = NNODES - 1;
            aR[it] = *(const uint4*)&Asrc[row * 128 + kofs + k];
            bR[it] = *(const uint4*)&W[r * 256 + kt * 64 + k];
        }
    };
    auto store_tile = [&](uint4* aR, uint4* bR) {
        #pragma unroll
        for (int it = 0; it < 4; ++it) {
            int b2 = (it * 2048 + tid * 8) * 2;   // byte offset
            *(uint4*)(AsB + swz(b2)) = aR[it];
            *(uint4*)(BsB + swz(b2)) = bR[it];
        }
    };

    f32x4 acc[4][4];
    const f32x4 zero = {0.f, 0.f, 0.f, 0.f};
    for (int m = 0; m < 4; ++m)
        for (int n = 0; n < 4; ++n) acc[m][n] = zero;

    const int lane = tid & 63, wid = tid >> 6;
    const int wr = wid >> 1, wc = wid & 1;
    const int l16 = lane & 15, lhi = lane >> 4;

    uint4 aCur[4], bCur[4], aNxt[4], bNxt[4];
    load_tile(0, aCur, bCur);

    #pragma unroll
    for (int kt = 0; kt < 4; ++kt) {
        if (kt < 3) load_tile(kt + 1, aNxt, bNxt);   // in flight during this kt
        __syncthreads();                              // prev kt's LDS reads done
        store_tile(aCur, bCur);                       // (waits on aCur/bCur only)
        __syncthreads();
        #pragma unroll
        for (int kk = 0; kk < 64; kk += 32) {
            short8 af[4], bf[4];
            #pragma unroll
            for (int m = 0; m < 4; ++m) {
                int row = wr * 64 + m * 16 + l16;
                af[m] = *(const short8*)(AsB + swz(row * 128 + (kk + lhi * 8) * 2));
            }
            #pragma unroll
            for (int n = 0; n < 4; ++n) {
                int row = wc * 64 + n * 16 + l16;
                bf[n] = *(const short8*)(BsB + swz(row * 128 + (kk + lhi * 8) * 2));
            }
            #pragma unroll
            for (int m = 0; m < 4; ++m)
                #pragma unroll
                for (int n = 0; n < 4; ++n)
                    acc[m][n] = __builtin_amdgcn_mfma_f32_16x16x32_bf16(af[m], bf[n], acc[m][n], 0, 0, 0);
        }
        #pragma unroll
        for (int it = 0; it < 4; ++it) { aCur[it] = aNxt[it]; bCur[it] = bNxt[it]; }
    }

    if (EPI == 0) {
        for (int n = 0; n < 4; ++n) {
            int col = wc * 64 + n * 16 + l16;
            float bv = bias[col];
            for (int m = 0; m < 4; ++m) {
                int row0 = bm + wr * 64 + m * 16 + lhi * 4;
                #pragma unroll
                for (int v = 0; v < 4; ++v) {
                    int row = row0 + v;
                    if (row < NNODES) {
                        float val = fmaxf(acc[m][n][v] + bv, 0.0f);
                        ((unsigned short*)outp)[row * 128 + col] = f2bf(val);
                    }
                }
            }
        }
    } else {
        float bv[4];
        #pragma unroll
        for (int n = 0; n < 4; ++n) bv[n] = bias[wc * 64 + n * 16 + l16];
        #pragma unroll
        for (int m = 0; m < 4; ++m) {
            #pragma unroll
            for (int v = 0; v < 4; ++v) {
                float s = 0.f;
                #pragma unroll
                for (int n = 0; n < 4; ++n) {
                    float val = acc[m][n][v] + bv[n];
                    acc[m][n][v] = val;
                    s += val * val;
                }
                s += __shfl_xor(s, 1); s += __shfl_xor(s, 2);
                s += __shfl_xor(s, 4); s += __shfl_xor(s, 8);
                if (l16 == 0) rss[wr * 64 + m * 16 + lhi * 4 + v][wc] = s;
            }
        }
        __syncthreads();
        float* out = (float*)outp;
        #pragma unroll
        for (int m = 0; m < 4; ++m) {
            #pragma unroll
            for (int v = 0; v < 4; ++v) {
                int r = wr * 64 + m * 16 + lhi * 4 + v;
                int row = bm + r;
                float tot = rss[r][0] + rss[r][1];
                float sc = 1.0f / fmaxf(sqrtf(tot), 1e-12f);
                if (row < NNODES) {
                    #pragma unroll
                    for (int n = 0; n < 4; ++n)
                        out[row * 128 + wc * 64 + n * 16 + l16] = acc[m][n][v] * sc;
                }
            }
        }
    }
}

// ---------------- launch ----------------

extern "C" void kernel_launch(void* const* d_in, const int* in_sizes, int n_in,
                              void* d_out, int out_size, void* d_ws, size_t ws_size,
                              hipStream_t stream) {
    const float* x   = (const float*)d_in[0];
    const int* ei    = (const int*)d_in[1];
    const float* W1l = (const float*)d_in[2];
    const float* b1  = (const float*)d_in[3];
    const float* W1r = (const float*)d_in[4];
    const float* W2l = (const float*)d_in[5];
    const float* b2  = (const float*)d_in[6];
    const float* W2r = (const float*)d_in[7];
    const int* srcp = ei;
    const int* dstp = ei + NEDGES;

    char* ws = (char*)d_ws;
    size_t off = 0;
    auto alloc = [&](size_t bytes) -> void* {
        void* p = ws + off;
        off += (bytes + 255) & ~(size_t)255;
        return p;
    };
    int* histmat = (int*)alloc((size_t)NBLK_E * NBUK * 4);
    int* colofs  = (int*)alloc((size_t)NBLK_E * NBUK * 4);
    int* totals  = (int*)alloc((size_t)NBUK * 4);
    int* bbase   = (int*)alloc((size_t)(NBUK + 1) * 4);
    int* rowptr  = (int*)alloc((size_t)(NNODES + 1) * 4);
    int* sorted  = (int*)alloc((size_t)NEDGES * 4);
    unsigned* ebuf = (unsigned*)alloc((size_t)NEDGES * 4);
    unsigned short* xb = (unsigned short*)alloc((size_t)NNODES * DDIM * 2);
    unsigned short* ag = (unsigned short*)alloc((size_t)NNODES * DDIM * 2);
    unsigned short* wc1 = (unsigned short*)alloc(128 * 256 * 2);
    unsigned short* wc2 = (unsigned short*)alloc(128 * 256 * 2);
    unsigned short* hb = xb;  // layer-1 output overwrites xb in place

    // CSR build: deterministic counting sort, zero per-edge global atomics
    p1_hist<<<NBLK_E, 256, 0, stream>>>(dstp, histmat);
    p2_colscan<<<(NBUK + 3) / 4, 256, 0, stream>>>(histmat, colofs, totals);
    p2b_bscan<<<1, 1024, 0, stream>>>(totals, bbase, rowptr);
    p3_bucket<<<NBLK_E, 256, 0, stream>>>(srcp, dstp, colofs, bbase, ebuf);
    p4_final<<<NBUK, 256, 0, stream>>>(ebuf, bbase, rowptr, sorted);

    // dtype prep
    sage_cvt<<<(NNODES * DDIM / 4 + 255) / 256, 256, 0, stream>>>(x, xb, NNODES * DDIM);
    sage_wprep2<<<256, 256, 0, stream>>>(W1l, W1r, W2l, W2r, wc1, wc2);

    const int aggr_grid = (NNODES + 3) / 4;
    const int gemm_grid = (NNODES + 127) / 128;

    // layer 1: h = relu(aggr@W1l.T + b1 + x@W1r.T)   (bf16, in place over xb)
    sage_aggr<<<aggr_grid, 256, 0, stream>>>(xb, rowptr, sorted, ag);
    sage_gemm<0><<<gemm_grid, 256, 0, stream>>>(ag, xb, wc1, b1, (void*)hb);
    // layer 2: out = normalize(aggr@W2l.T + b2 + h@W2r.T)  (f32, norm fused)
    sage_aggr<<<aggr_grid, 256, 0, stream>>>(hb, rowptr, sorted, ag);
    sage_gemm<1><<<gemm_grid, 256, 0, stream>>>(ag, hb, wc2, b2, d_out);
}

// Round 14
// 358.974 us; speedup vs baseline: 1.3489x; 1.3489x over previous
//
#include <hip/hip_runtime.h>

#define NNODES 100000
#define NEDGES 1600000
#define DDIM   128
#define NBUK ((NNODES + 127) / 128)        // 782 buckets of 128 nodes
#define EB   8192                          // edges per sort block
#define NBLK_E ((NEDGES + EB - 1) / EB)    // 196

typedef __attribute__((ext_vector_type(8))) short short8;
typedef __attribute__((ext_vector_type(4))) float f32x4;
typedef __attribute__((ext_vector_type(2))) float f32x2;

// f32 -> bf16 round-to-nearest-even (bit trick; NaN irrelevant here)
__device__ __forceinline__ unsigned short f2bf(float f) {
    unsigned u = __float_as_uint(f);
    u += 0x7FFFu + ((u >> 16) & 1u);
    return (unsigned short)(u >> 16);
}

// ---------------- CSR build: deterministic bucketed counting sort ----------------
// No per-edge GLOBAL atomics anywhere (round-5 lesson: 1.6M atomics / 782 addrs
// serialize at ~210ns per same-line RMW = 431us). All per-edge atomics are LDS.

__global__ void __launch_bounds__(256) p1_hist(const int* __restrict__ dst,
                                               int* __restrict__ histmat) {
    __shared__ int h[NBUK];
    for (int i = threadIdx.x; i < NBUK; i += 256) h[i] = 0;
    __syncthreads();
    int base = blockIdx.x * EB;
    int end = base + EB; if (end > NEDGES) end = NEDGES;
    for (int i = base + threadIdx.x; i < end; i += 256)
        atomicAdd(&h[dst[i] >> 7], 1);
    __syncthreads();
    for (int i = threadIdx.x; i < NBUK; i += 256)
        histmat[blockIdx.x * NBUK + i] = h[i];
}

__global__ void __launch_bounds__(256) p2_colscan(const int* __restrict__ histmat,
                                                  int* __restrict__ colofs,
                                                  int* __restrict__ totals) {
    int b = blockIdx.x * 4 + (threadIdx.x >> 6);
    if (b >= NBUK) return;
    int lane = threadIdx.x & 63;
    int running = 0;
    #pragma unroll
    for (int r = 0; r < (NBLK_E + 63) / 64; ++r) {
        int blk = r * 64 + lane;
        int v = (blk < NBLK_E) ? histmat[blk * NBUK + b] : 0;
        int sc = v;
        for (int o = 1; o < 64; o <<= 1) {
            int u = __shfl_up(sc, o);
            if (lane >= o) sc += u;
        }
        if (blk < NBLK_E) colofs[blk * NBUK + b] = running + sc - v;
        running += __shfl(sc, 63);
    }
    if (lane == 0) totals[b] = running;
}

__global__ void __launch_bounds__(1024) p2b_bscan(const int* __restrict__ totals,
                                                  int* __restrict__ bbase,
                                                  int* __restrict__ rowptr) {
    __shared__ int sm[1024];
    int t = threadIdx.x;
    int v = (t < NBUK) ? totals[t] : 0;
    sm[t] = v;
    __syncthreads();
    for (int o = 1; o < 1024; o <<= 1) {
        int u = (t >= o) ? sm[t - o] : 0;
        __syncthreads();
        sm[t] += u;
        __syncthreads();
    }
    if (t < NBUK) bbase[t] = sm[t] - v;
    if (t == 0) { bbase[NBUK] = NEDGES; rowptr[NNODES] = NEDGES; }
}

__global__ void __launch_bounds__(256) p3_bucket(const int* __restrict__ src,
                                                 const int* __restrict__ dst,
                                                 const int* __restrict__ colofs,
                                                 const int* __restrict__ bbase,
                                                 unsigned* __restrict__ ebuf) {
    __shared__ int cur[NBUK];
    for (int i = threadIdx.x; i < NBUK; i += 256)
        cur[i] = bbase[i] + colofs[blockIdx.x * NBUK + i];
    __syncthreads();
    int base = blockIdx.x * EB;
    int end = base + EB; if (end > NEDGES) end = NEDGES;
    for (int i = base + threadIdx.x; i < end; i += 256) {
        int d = dst[i];
        int pos = atomicAdd(&cur[d >> 7], 1);
        ebuf[pos] = ((unsigned)(d & 127) << 17) | (unsigned)src[i];
    }
}

__global__ void __launch_bounds__(256) p4_final(const unsigned* __restrict__ ebuf,
                                                const int* __restrict__ bbase,
                                                int* __restrict__ rowptr,
                                                int* __restrict__ sorted) {
    __shared__ int cnt[128];
    __shared__ int ofs[128];
    int b = blockIdx.x;
    int s = bbase[b], e = bbase[b + 1];
    int t = threadIdx.x;
    if (t < 128) cnt[t] = 0;
    __syncthreads();
    for (int i = s + t; i < e; i += 256)
        atomicAdd(&cnt[ebuf[i] >> 17], 1);
    __syncthreads();
    if (t < 128) ofs[t] = cnt[t];
    __syncthreads();
    for (int o = 1; o < 128; o <<= 1) {
        int u = (t >= o && t < 128) ? ofs[t - o] : 0;
        __syncthreads();
        if (t < 128) ofs[t] += u;
        __syncthreads();
    }
    int nodebase = b << 7;
    if (t < 128) {
        int excl = ofs[t] - cnt[t];
        if (nodebase + t < NNODES) rowptr[nodebase + t] = s + excl;
        cnt[t] = excl;  // reuse as cursor
    }
    __syncthreads();
    for (int i = s + t; i < e; i += 256) {
        unsigned v = ebuf[i];
        int r = atomicAdd(&cnt[v >> 17], 1);
        sorted[s + r] = (int)(v & 0x1FFFFu);
    }
}

// ---------------- dtype prep ----------------

__global__ void sage_cvt(const float* __restrict__ in, unsigned short* __restrict__ out, int n) {
    int i = (blockIdx.x * blockDim.x + threadIdx.x) * 4;
    if (i < n) {
        float4 v = *(const float4*)&in[i];
        uint2 o;
        o.x = (unsigned)f2bf(v.x) | ((unsigned)f2bf(v.y) << 16);
        o.y = (unsigned)f2bf(v.z) | ((unsigned)f2bf(v.w) << 16);
        *(uint2*)&out[i] = o;
    }
}

__global__ void sage_wprep2(const float* __restrict__ W1l, const float* __restrict__ W1r,
                            const float* __restrict__ W2l, const float* __restrict__ W2r,
                            unsigned short* __restrict__ wc1, unsigned short* __restrict__ wc2) {
    int idx = blockIdx.x * blockDim.x + threadIdx.x;  // 0..65535
    int which = idx >> 15;
    int id = idx & 32767;
    int j = id >> 8, k = id & 255;
    const float* Wl = which ? W2l : W1l;
    const float* Wr = which ? W2r : W1r;
    unsigned short* o = which ? wc2 : wc1;
    float v = (k < 128) ? Wl[j * 128 + k] : Wr[j * 128 + (k - 128)];
    o[id] = f2bf(v);
}

// ---------------- aggregation (one wave per node, dwordx4 gather) ----------------

__global__ void __launch_bounds__(256) sage_aggr(const unsigned short* __restrict__ in,
                                                 const int* __restrict__ rowptr,
                                                 const int* __restrict__ srcs,
                                                 unsigned short* __restrict__ ag) {
    int node = blockIdx.x * 4 + (threadIdx.x >> 6);
    if (node >= NNODES) return;
    int lane = threadIdx.x & 63;
    int g = lane >> 4, s = lane & 15;
    int beg = rowptr[node], end = rowptr[node + 1];
    const uint4* inq = (const uint4*)in;   // 16 uint4 per row
    f32x2 f0 = {0.f, 0.f}, f1 = {0.f, 0.f}, f2 = {0.f, 0.f}, f3 = {0.f, 0.f};

    auto accum = [&](uint4 v) {
        f0 += (f32x2){__uint_as_float(v.x << 16), __uint_as_float(v.x & 0xFFFF0000u)};
        f1 += (f32x2){__uint_as_float(v.y << 16), __uint_as_float(v.y & 0xFFFF0000u)};
        f2 += (f32x2){__uint_as_float(v.z << 16), __uint_as_float(v.z & 0xFFFF0000u)};
        f3 += (f32x2){__uint_as_float(v.w << 16), __uint_as_float(v.w & 0xFFFF0000u)};
    };

    int i = beg;
    for (; i + 16 <= end; i += 16) {
        uint4 va = inq[srcs[i + g] * 16 + s];
        uint4 vb = inq[srcs[i + 4 + g] * 16 + s];
        uint4 vc = inq[srcs[i + 8 + g] * 16 + s];
        uint4 vd = inq[srcs[i + 12 + g] * 16 + s];
        accum(va); accum(vb); accum(vc); accum(vd);
    }
    for (; i + 4 <= end; i += 4)
        accum(inq[srcs[i + g] * 16 + s]);
    if (i + g < end)
        accum(inq[srcs[i + g] * 16 + s]);

    f0.x += __shfl_xor(f0.x, 16); f0.y += __shfl_xor(f0.y, 16);
    f1.x += __shfl_xor(f1.x, 16); f1.y += __shfl_xor(f1.y, 16);
    f2.x += __shfl_xor(f2.x, 16); f2.y += __shfl_xor(f2.y, 16);
    f3.x += __shfl_xor(f3.x, 16); f3.y += __shfl_xor(f3.y, 16);
    f0.x += __shfl_xor(f0.x, 32); f0.y += __shfl_xor(f0.y, 32);
    f1.x += __shfl_xor(f1.x, 32); f1.y += __shfl_xor(f1.y, 32);
    f2.x += __shfl_xor(f2.x, 32); f2.y += __shfl_xor(f2.y, 32);
    f3.x += __shfl_xor(f3.x, 32); f3.y += __shfl_xor(f3.y, 32);

    int cnt = end - beg;
    float inv = (cnt > 0) ? 1.0f / (float)cnt : 0.0f;
    if (g == 0) {
        uint4 o;
        o.x = (unsigned)f2bf(f0.x * inv) | ((unsigned)f2bf(f0.y * inv) << 16);
        o.y = (unsigned)f2bf(f1.x * inv) | ((unsigned)f2bf(f1.y * inv) << 16);
        o.z = (unsigned)f2bf(f2.x * inv) | ((unsigned)f2bf(f2.y * inv) << 16);
        o.w = (unsigned)f2bf(f3.x * inv) | ((unsigned)f2bf(f3.y * inv) << 16);
        ((uint4*)ag)[node * 16 + s] = o;
    }
}

// ---------------- GEMM: out[i][j] = sum_k Acat[i][k]*W[j][k] + bias[j] ----------------
// Round-11 staging structure (known-good 63us) + XOR-swizzled LDS (round-13's
// only verified win: bank conflicts 2.4M -> 0). NO lambda/pointer staging
// (round-13 lesson: address-taken register arrays -> scratch -> 247MB writes).
// EPI 0: relu + bf16 store.  EPI 1: f32 store with fused row L2-normalize.

__device__ __forceinline__ int swz(int byteoff) {
    return byteoff ^ ((byteoff >> 3) & 0x70);   // col2 ^= (row&7)<<4
}

template <int EPI>
__global__ void __launch_bounds__(256) sage_gemm(const unsigned short* __restrict__ A0,
                                                 const unsigned short* __restrict__ A1,
                                                 const unsigned short* __restrict__ W,
                                                 const float* __restrict__ bias,
                                                 void* __restrict__ outp) {
    __shared__ unsigned short As[128 * 64];
    __shared__ unsigned short Bs[128 * 64];
    __shared__ float rss[128][2];
    const int tid = threadIdx.x;
    const int bm = blockIdx.x * 128;
    char* AsB = (char*)As;
    char* BsB = (char*)Bs;

    f32x4 acc[4][4];
    const f32x4 zero = {0.f, 0.f, 0.f, 0.f};
    for (int m = 0; m < 4; ++m)
        for (int n = 0; n < 4; ++n) acc[m][n] = zero;

    const int lane = tid & 63, wid = tid >> 6;
    const int wr = wid >> 1, wc = wid & 1;
    const int l16 = lane & 15, lhi = lane >> 4;

    for (int kt = 0; kt < 4; ++kt) {
        const unsigned short* Asrc = (kt < 2) ? A0 : A1;
        const int kofs = (kt & 1) * 64;
        __syncthreads();   // previous kt's LDS reads complete before overwrite
        #pragma unroll
        for (int it = 0; it < 4; ++it) {
            int idx = it * 2048 + tid * 8;
            int r = idx >> 6, k = idx & 63;
            int row = bm + r; if (row >= NNODES) row = NNODES - 1;
            uint4 av = *(const uint4*)&Asrc[row * 128 + kofs + k];
            uint4 bv = *(const uint4*)&W[r * 256 + kt * 64 + k];
            int b2 = idx * 2;   // byte offset in tile
            *(uint4*)(AsB + swz(b2)) = av;
            *(uint4*)(BsB + swz(b2)) = bv;
        }
        __syncthreads();
        #pragma unroll
        for (int kk = 0; kk < 64; kk += 32) {
            short8 af[4], bf[4];
            #pragma unroll
            for (int m = 0; m < 4; ++m) {
                int row = wr * 64 + m * 16 + l16;
                af[m] = *(const short8*)(AsB + swz(row * 128 + (kk + lhi * 8) * 2));
            }
            #pragma unroll
            for (int n = 0; n < 4; ++n) {
                int row = wc * 64 + n * 16 + l16;
                bf[n] = *(const short8*)(BsB + swz(row * 128 + (kk + lhi * 8) * 2));
            }
            #pragma unroll
            for (int m = 0; m < 4; ++m)
                #pragma unroll
                for (int n = 0; n < 4; ++n)
                    acc[m][n] = __builtin_amdgcn_mfma_f32_16x16x32_bf16(af[m], bf[n], acc[m][n], 0, 0, 0);
        }
    }

    if (EPI == 0) {
        for (int n = 0; n < 4; ++n) {
            int col = wc * 64 + n * 16 + l16;
            float bv = bias[col];
            for (int m = 0; m < 4; ++m) {
                int row0 = bm + wr * 64 + m * 16 + lhi * 4;
                #pragma unroll
                for (int v = 0; v < 4; ++v) {
                    int row = row0 + v;
                    if (row < NNODES) {
                        float val = fmaxf(acc[m][n][v] + bv, 0.0f);
                        ((unsigned short*)outp)[row * 128 + col] = f2bf(val);
                    }
                }
            }
        }
    } else {
        float bv[4];
        #pragma unroll
        for (int n = 0; n < 4; ++n) bv[n] = bias[wc * 64 + n * 16 + l16];
        #pragma unroll
        for (int m = 0; m < 4; ++m) {
            #pragma unroll
            for (int v = 0; v < 4; ++v) {
                float s = 0.f;
                #pragma unroll
                for (int n = 0; n < 4; ++n) {
                    float val = acc[m][n][v] + bv[n];
                    acc[m][n][v] = val;
                    s += val * val;
                }
                s += __shfl_xor(s, 1); s += __shfl_xor(s, 2);
                s += __shfl_xor(s, 4); s += __shfl_xor(s, 8);
                if (l16 == 0) rss[wr * 64 + m * 16 + lhi * 4 + v][wc] = s;
            }
        }
        __syncthreads();
        float* out = (float*)outp;
        #pragma unroll
        for (int m = 0; m < 4; ++m) {
            #pragma unroll
            for (int v = 0; v < 4; ++v) {
                int r = wr * 64 + m * 16 + lhi * 4 + v;
                int row = bm + r;
                float tot = rss[r][0] + rss[r][1];
                float sc = 1.0f / fmaxf(sqrtf(tot), 1e-12f);
                if (row < NNODES) {
                    #pragma unroll
                    for (int n = 0; n < 4; ++n)
                        out[row * 128 + wc * 64 + n * 16 + l16] = acc[m][n][v] * sc;
                }
            }
        }
    }
}

// ---------------- launch ----------------

extern "C" void kernel_launch(void* const* d_in, const int* in_sizes, int n_in,
                              void* d_out, int out_size, void* d_ws, size_t ws_size,
                              hipStream_t stream) {
    const float* x   = (const float*)d_in[0];
    const int* ei    = (const int*)d_in[1];
    const float* W1l = (const float*)d_in[2];
    const float* b1  = (const float*)d_in[3];
    const float* W1r = (const float*)d_in[4];
    const float* W2l = (const float*)d_in[5];
    const float* b2  = (const float*)d_in[6];
    const float* W2r = (const float*)d_in[7];
    const int* srcp = ei;
    const int* dstp = ei + NEDGES;

    char* ws = (char*)d_ws;
    size_t off = 0;
    auto alloc = [&](size_t bytes) -> void* {
        void* p = ws + off;
        off += (bytes + 255) & ~(size_t)255;
        return p;
    };
    int* histmat = (int*)alloc((size_t)NBLK_E * NBUK * 4);
    int* colofs  = (int*)alloc((size_t)NBLK_E * NBUK * 4);
    int* totals  = (int*)alloc((size_t)NBUK * 4);
    int* bbase   = (int*)alloc((size_t)(NBUK + 1) * 4);
    int* rowptr  = (int*)alloc((size_t)(NNODES + 1) * 4);
    int* sorted  = (int*)alloc((size_t)NEDGES * 4);
    unsigned* ebuf = (unsigned*)alloc((size_t)NEDGES * 4);
    unsigned short* xb = (unsigned short*)alloc((size_t)NNODES * DDIM * 2);
    unsigned short* ag = (unsigned short*)alloc((size_t)NNODES * DDIM * 2);
    unsigned short* wc1 = (unsigned short*)alloc(128 * 256 * 2);
    unsigned short* wc2 = (unsigned short*)alloc(128 * 256 * 2);
    unsigned short* hb = xb;  // layer-1 output overwrites xb in place

    // CSR build: deterministic counting sort, zero per-edge global atomics
    p1_hist<<<NBLK_E, 256, 0, stream>>>(dstp, histmat);
    p2_colscan<<<(NBUK + 3) / 4, 256, 0, stream>>>(histmat, colofs, totals);
    p2b_bscan<<<1, 1024, 0, stream>>>(totals, bbase, rowptr);
    p3_bucket<<<NBLK_E, 256, 0, stream>>>(srcp, dstp, colofs, bbase, ebuf);
    p4_final<<<NBUK, 256, 0, stream>>>(ebuf, bbase, rowptr, sorted);

    // dtype prep
    sage_cvt<<<(NNODES * DDIM / 4 + 255) / 256, 256, 0, stream>>>(x, xb, NNODES * DDIM);
    sage_wprep2<<<256, 256, 0, stream>>>(W1l, W1r, W2l, W2r, wc1, wc2);

    const int aggr_grid = (NNODES + 3) / 4;
    const int gemm_grid = (NNODES + 127) / 128;

    // layer 1: h = relu(aggr@W1l.T + b1 + x@W1r.T)   (bf16, in place over xb)
    sage_aggr<<<aggr_grid, 256, 0, stream>>>(xb, rowptr, sorted, ag);
    sage_gemm<0><<<gemm_grid, 256, 0, stream>>>(ag, xb, wc1, b1, (void*)hb);
    // layer 2: out = normalize(aggr@W2l.T + b2 + h@W2r.T)  (f32, norm fused)
    sage_aggr<<<aggr_grid, 256, 0, stream>>>(hb, rowptr, sorted, ag);
    sage_gemm<1><<<gemm_grid, 256, 0, stream>>>(ag, hb, wc2, b2, d_out);
}